// Round 1
// baseline (674.637 us; speedup 1.0000x reference)
//
#include <hip/hip_runtime.h>

// Transformer block fwd: B=128, T=256, E=512, H=8, D=64, F=2048, fp32 in/out.
// Strategy: bf16 MFMA for all matmuls (threshold 0.109 abs allows it),
// fp32 accumulation + fp32 residual stream.

typedef unsigned short u16;
typedef short short8 __attribute__((ext_vector_type(8)));
typedef float f32x4 __attribute__((ext_vector_type(4)));

#define BB 128
#define TT 256
#define EE 512
#define HH 8
#define DD 64
#define FF 2048
#define BT (BB * TT)          // 32768 rows

__device__ __forceinline__ u16 f2b(float f) {
  union { float f; unsigned int u; } v; v.f = f;
  unsigned int u = v.u + 0x7fffu + ((v.u >> 16) & 1u);   // RNE
  return (u16)(u >> 16);
}

__device__ __forceinline__ f32x4 mfma16(short8 a, short8 b, f32x4 c) {
  return __builtin_amdgcn_mfma_f32_16x16x32_bf16(a, b, c, 0, 0, 0);
}

// ---------------- weight prep: convert + transpose to [N][K] bf16 ----------------

// Wq/Wk/Wv [H,E,D] fp32 -> WqkvT [1536][512] bf16, row n = which*512 + h*64 + d
__global__ __launch_bounds__(256) void conv_qkv(const float* __restrict__ Wq,
                                                const float* __restrict__ Wk,
                                                const float* __restrict__ Wv,
                                                u16* __restrict__ dst) {
  const int n = blockIdx.x;                    // 0..1535
  const int which = n >> 9, hd = n & 511;
  const int h = hd >> 6, d = hd & 63;
  const float* W = (which == 0) ? Wq : (which == 1) ? Wk : Wv;
  const float* src = W + (size_t)h * EE * DD + d;   // stride DD over e
  u16* drow = dst + (size_t)n * EE;
  for (int e = threadIdx.x; e < EE; e += 256)
    drow[e] = f2b(src[(size_t)e * DD]);
}

// generic: src [K][N] fp32 -> dst [N][K] bf16
__global__ __launch_bounds__(256) void conv_t(const float* __restrict__ src,
                                              u16* __restrict__ dst, int K, int N) {
  const int n = blockIdx.x;
  u16* drow = dst + (size_t)n * K;
  for (int k = threadIdx.x; k < K; k += 256)
    drow[k] = f2b(src[(size_t)k * N + n]);
}

// ---------------- LayerNorm: fp32 in -> bf16 out, one wave per row (E=512) -------

__global__ __launch_bounds__(256) void ln_fwd(const float* __restrict__ xin,
                                              const float* __restrict__ g,
                                              const float* __restrict__ bb,
                                              u16* __restrict__ out) {
  const int wid = threadIdx.x >> 6, lane = threadIdx.x & 63;
  const size_t row = (size_t)blockIdx.x * 4 + wid;
  const float* xr = xin + row * EE + lane * 8;
  float v[8];
  *(float4*)(v)     = *(const float4*)(xr);
  *(float4*)(v + 4) = *(const float4*)(xr + 4);
  float s = 0.f;
#pragma unroll
  for (int j = 0; j < 8; j++) s += v[j];
#pragma unroll
  for (int d = 1; d < 64; d <<= 1) s += __shfl_xor(s, d);
  const float mu = s * (1.f / 512.f);
  float q = 0.f;
#pragma unroll
  for (int j = 0; j < 8; j++) { float dd = v[j] - mu; q += dd * dd; }
#pragma unroll
  for (int d = 1; d < 64; d <<= 1) q += __shfl_xor(q, d);
  const float rstd = rsqrtf(q * (1.f / 512.f) + 1e-5f);
  float gv[8], bv[8];
  *(float4*)(gv)     = *(const float4*)(g + lane * 8);
  *(float4*)(gv + 4) = *(const float4*)(g + lane * 8 + 4);
  *(float4*)(bv)     = *(const float4*)(bb + lane * 8);
  *(float4*)(bv + 4) = *(const float4*)(bb + lane * 8 + 4);
  short8 o;
#pragma unroll
  for (int j = 0; j < 8; j++) o[j] = (short)f2b((v[j] - mu) * rstd * gv[j] + bv[j]);
  *(short8*)(out + row * EE + lane * 8) = o;
}

// ---------------- GEMM: C[M,N] = A[M,K](bf16) @ Bt[N,K]^T(bf16), epilogue opts ----
// 128x128 tile, BK=32, 256 threads = 4 waves (2x2 of 64x64), 16x16x32 MFMA.

template <bool BIAS, bool RELU, bool RES, bool OUTBF>
__global__ __launch_bounds__(256) void gemm_bt(const u16* __restrict__ A,
                                               const u16* __restrict__ Bt,
                                               const float* __restrict__ bias,
                                               const float* __restrict__ res,
                                               void* __restrict__ out,
                                               int M, int N, int K) {
  __shared__ u16 As[128][48];   // stride 48 elems = 96B (16B-aligned rows, depads banks)
  __shared__ u16 Bs[128][48];
  const int tid = threadIdx.x;
  const int wid = tid >> 6, lane = tid & 63;
  const int llo = lane & 15, lhi = lane >> 4;
  const int wr = (wid >> 1) * 64, wc = (wid & 1) * 64;
  const size_t row0 = (size_t)blockIdx.y * 128;
  const size_t col0 = (size_t)blockIdx.x * 128;

  f32x4 acc[4][4];
#pragma unroll
  for (int m = 0; m < 4; m++)
#pragma unroll
    for (int n = 0; n < 4; n++) acc[m][n] = (f32x4){0.f, 0.f, 0.f, 0.f};

  for (int k0 = 0; k0 < K; k0 += 32) {
    __syncthreads();
#pragma unroll
    for (int p = 0; p < 2; p++) {
      const int c = p * 256 + tid;          // 512 chunks of 8 elems
      const int r = c >> 2, cc = (c & 3) * 8;
      *(short8*)(&As[r][cc]) = *(const short8*)(A + (row0 + r) * K + k0 + cc);
      *(short8*)(&Bs[r][cc]) = *(const short8*)(Bt + (col0 + r) * K + k0 + cc);
    }
    __syncthreads();
    short8 af[4], bf[4];
#pragma unroll
    for (int m = 0; m < 4; m++) af[m] = *(const short8*)(&As[wr + m * 16 + llo][lhi * 8]);
#pragma unroll
    for (int n = 0; n < 4; n++) bf[n] = *(const short8*)(&Bs[wc + n * 16 + llo][lhi * 8]);
#pragma unroll
    for (int m = 0; m < 4; m++)
#pragma unroll
      for (int n = 0; n < 4; n++) acc[m][n] = mfma16(af[m], bf[n], acc[m][n]);
  }

#pragma unroll
  for (int m = 0; m < 4; m++)
#pragma unroll
    for (int r = 0; r < 4; r++) {
      const size_t row = row0 + wr + m * 16 + lhi * 4 + r;
#pragma unroll
      for (int n = 0; n < 4; n++) {
        const size_t col = col0 + wc + n * 16 + llo;
        float v = acc[m][n][r];
        if (BIAS) v += bias[col];
        if (RELU) v = fmaxf(v, 0.f);
        if (RES) v += res[row * (size_t)N + col];
        if (OUTBF) ((u16*)out)[row * (size_t)N + col] = f2b(v);
        else       ((float*)out)[row * (size_t)N + col] = v;
      }
    }
}

// ---------------- Flash attention: one block per (b,h), wave w = Q rows [64w,64w+64) ----
// qkv [BT][1536] bf16 (q|k|v each 512 cols, head h at h*64). ctx [BT][512] bf16.

__global__ __launch_bounds__(256) void attn_fwd(const u16* __restrict__ qkv,
                                                u16* __restrict__ ctx) {
  const int bh = blockIdx.x;                 // 0..1023
  const int b = bh >> 3, h = bh & 7;
  const int wid = threadIdx.x >> 6;
  const int lane = threadIdx.x & 63;
  const int llo = lane & 15, lhi = lane >> 4;
  const int t0 = wid * 64;

  __shared__ u16 Pl[4][64][32];              // per-wave P staging (16 KB)

  const u16* qp = qkv + (size_t)b * TT * 1536 + h * 64;
  const u16* kp = qp + 512;
  const u16* vp = qp + 1024;

  short8 qf[4][2];
#pragma unroll
  for (int m = 0; m < 4; m++)
#pragma unroll
    for (int k2 = 0; k2 < 2; k2++) {
      const int t = t0 + m * 16 + llo;
      qf[m][k2] = *(const short8*)(qp + (size_t)t * 1536 + k2 * 32 + lhi * 8);
    }

  f32x4 O[4][4];
  float mrow[4][4], lrow[4][4];
#pragma unroll
  for (int m = 0; m < 4; m++) {
#pragma unroll
    for (int n = 0; n < 4; n++) O[m][n] = (f32x4){0.f, 0.f, 0.f, 0.f};
#pragma unroll
    for (int r = 0; r < 4; r++) { mrow[m][r] = -1e30f; lrow[m][r] = 0.f; }
  }

  const int nst = (t0 + 64) >> 5;            // causal: s-tiles of 32 up to wave's max row
  for (int st = 0; st < nst; st++) {
    const int s0 = st * 32;
    f32x4 S[4][2];
#pragma unroll
    for (int m = 0; m < 4; m++) {
      S[m][0] = (f32x4){0.f, 0.f, 0.f, 0.f};
      S[m][1] = (f32x4){0.f, 0.f, 0.f, 0.f};
    }
#pragma unroll
    for (int k2 = 0; k2 < 2; k2++) {
      const short8 b0 = *(const short8*)(kp + (size_t)(s0 + llo) * 1536 + k2 * 32 + lhi * 8);
      const short8 b1 = *(const short8*)(kp + (size_t)(s0 + 16 + llo) * 1536 + k2 * 32 + lhi * 8);
#pragma unroll
      for (int m = 0; m < 4; m++) {
        S[m][0] = mfma16(qf[m][k2], b0, S[m][0]);
        S[m][1] = mfma16(qf[m][k2], b1, S[m][1]);
      }
    }
    // online softmax update (rows owned by 16-lane groups; reduce over llo)
#pragma unroll
    for (int m = 0; m < 4; m++) {
      float sf[4];
#pragma unroll
      for (int r = 0; r < 4; r++) {
        const int t = t0 + m * 16 + lhi * 4 + r;
        float v0 = S[m][0][r] * 0.125f;
        float v1 = S[m][1][r] * 0.125f;
        if (s0 + llo > t)      v0 = -1e30f;
        if (s0 + 16 + llo > t) v1 = -1e30f;
        float mx = fmaxf(v0, v1);
#pragma unroll
        for (int d = 1; d < 16; d <<= 1) mx = fmaxf(mx, __shfl_xor(mx, d));
        const float mnew = fmaxf(mrow[m][r], mx);
        const float sc = __expf(mrow[m][r] - mnew);
        mrow[m][r] = mnew;
        const float p0 = __expf(v0 - mnew);
        const float p1 = __expf(v1 - mnew);
        float rs = p0 + p1;
#pragma unroll
        for (int d = 1; d < 16; d <<= 1) rs += __shfl_xor(rs, d);
        lrow[m][r] = lrow[m][r] * sc + rs;
        sf[r] = sc;
        const int pr = m * 16 + lhi * 4 + r;
        Pl[wid][pr][llo]      = f2b(p0);
        Pl[wid][pr][llo + 16] = f2b(p1);
      }
#pragma unroll
      for (int n = 0; n < 4; n++)
#pragma unroll
        for (int r = 0; r < 4; r++) O[m][n][r] *= sf[r];
    }
    // PV: O[64,64] += P[64,32] @ V[32,64]
    short8 pf[4];
#pragma unroll
    for (int m = 0; m < 4; m++)
      pf[m] = *(const short8*)(&Pl[wid][m * 16 + llo][lhi * 8]);
#pragma unroll
    for (int n = 0; n < 4; n++) {
      short8 vf;
#pragma unroll
      for (int j = 0; j < 8; j++)
        vf[j] = (short)vp[(size_t)(s0 + lhi * 8 + j) * 1536 + n * 16 + llo];
#pragma unroll
      for (int m = 0; m < 4; m++) O[m][n] = mfma16(pf[m], vf, O[m][n]);
    }
  }

#pragma unroll
  for (int m = 0; m < 4; m++)
#pragma unroll
    for (int r = 0; r < 4; r++) {
      const int t = t0 + m * 16 + lhi * 4 + r;
      const float inv = 1.f / lrow[m][r];
      u16* orow = ctx + ((size_t)b * TT + t) * EE + h * 64;
#pragma unroll
      for (int n = 0; n < 4; n++)
        orow[n * 16 + llo] = f2b(O[m][n][r] * inv);
    }
}

// ---------------- launch ----------------

extern "C" void kernel_launch(void* const* d_in, const int* in_sizes, int n_in,
                              void* d_out, int out_size, void* d_ws, size_t ws_size,
                              hipStream_t stream) {
  const float* x   = (const float*)d_in[0];
  const float* Wq  = (const float*)d_in[1];
  const float* Wk  = (const float*)d_in[2];
  const float* Wv  = (const float*)d_in[3];
  const float* Wo  = (const float*)d_in[4];
  const float* bo  = (const float*)d_in[5];
  const float* g1  = (const float*)d_in[6];
  const float* be1 = (const float*)d_in[7];
  const float* g2  = (const float*)d_in[8];
  const float* be2 = (const float*)d_in[9];
  const float* W1  = (const float*)d_in[10];
  const float* b1  = (const float*)d_in[11];
  const float* W2  = (const float*)d_in[12];
  const float* b2  = (const float*)d_in[13];
  float* out = (float*)d_out;

  // workspace layout (~198 MB total)
  char* w = (char*)d_ws;
  u16* WqkvT = (u16*)w;                 w += (size_t)1536 * 512 * 2;   // 1.5 MB
  u16* WoT   = (u16*)w;                 w += (size_t)512 * 512 * 2;    // 0.5 MB
  u16* W1T   = (u16*)w;                 w += (size_t)2048 * 512 * 2;   // 2 MB
  u16* W2T   = (u16*)w;                 w += (size_t)512 * 2048 * 2;   // 2 MB
  u16* hbuf  = (u16*)w;                 w += (size_t)BT * EE * 2;      // 32 MB (h / h2)
  u16* ctxb  = (u16*)w;                 w += (size_t)BT * EE * 2;      // 32 MB
  u16* big   = (u16*)w;                                               // 128 MB (qkv / ff1)
  u16* qkvb = big;
  u16* ff1  = big;

  // 1. weight prep (bf16 + transpose to [N][K])
  conv_qkv<<<1536, 256, 0, stream>>>(Wq, Wk, Wv, WqkvT);
  conv_t<<<512,  256, 0, stream>>>(Wo, WoT, 512, 512);
  conv_t<<<2048, 256, 0, stream>>>(W1, W1T, 512, 2048);
  conv_t<<<512,  256, 0, stream>>>(W2, W2T, 2048, 512);

  // 2. LN1: h = ln(x)
  ln_fwd<<<BT / 4, 256, 0, stream>>>(x, g1, be1, hbuf);

  // 3. QKV: qkv = h @ WqkvT^T   [BT,1536] bf16
  gemm_bt<false, false, false, true><<<dim3(1536 / 128, BT / 128), 256, 0, stream>>>(
      hbuf, WqkvT, nullptr, nullptr, qkvb, BT, 1536, 512);

  // 4. attention -> ctx [BT,512] bf16
  attn_fwd<<<BB * HH, 256, 0, stream>>>(qkvb, ctxb);

  // 5. proj: out1 = ctx @ Wo + bo + x  (fp32, into d_out)
  gemm_bt<true, false, true, false><<<dim3(512 / 128, BT / 128), 256, 0, stream>>>(
      ctxb, WoT, bo, x, out, BT, 512, 512);

  // 6. LN2: h2 = ln(out1)  (reuse hbuf)
  ln_fwd<<<BT / 4, 256, 0, stream>>>(out, g2, be2, hbuf);

  // 7. FFN1: ff1 = relu(h2 @ W1 + b1)  [BT,2048] bf16 (reuses qkv region)
  gemm_bt<true, true, false, true><<<dim3(2048 / 128, BT / 128), 256, 0, stream>>>(
      hbuf, W1T, b1, nullptr, ff1, BT, 2048, 512);

  // 8. FFN2: out = out1 + ff1 @ W2 + b2  (in-place residual on d_out)
  gemm_bt<true, false, true, false><<<dim3(512 / 128, BT / 128), 256, 0, stream>>>(
      ff1, W2T, b2, out, out, BT, 512, 2048);
}

// Round 2
// 648.839 us; speedup vs baseline: 1.0398x; 1.0398x over previous
//
#include <hip/hip_runtime.h>

// Transformer block fwd: B=128, T=256, E=512, H=8, D=64, F=2048, fp32 in/out.
// bf16 MFMA everywhere (abs threshold 0.109 >> bf16 error ~0.03), fp32 residual.
// R2: m97-style GEMM (global_load_lds w16, linear LDS, XCD swizzle),
//     attention V^T staged in LDS, tiled coalesced weight transposes.

typedef unsigned short u16;
typedef short short8 __attribute__((ext_vector_type(8)));
typedef float f32x4 __attribute__((ext_vector_type(4)));

#define BB 128
#define TT 256
#define EE 512
#define HH 8
#define DD 64
#define FF 2048
#define BT (BB * TT)          // 32768 rows

__device__ __forceinline__ u16 f2b(float f) {
  union { float f; unsigned int u; } v; v.f = f;
  unsigned int u = v.u + 0x7fffu + ((v.u >> 16) & 1u);   // RNE
  return (u16)(u >> 16);
}

__device__ __forceinline__ f32x4 mfma16(short8 a, short8 b, f32x4 c) {
  return __builtin_amdgcn_mfma_f32_16x16x32_bf16(a, b, c, 0, 0, 0);
}

// async global->LDS, 16B per lane; LDS dest = wave-uniform base + lane*16
__device__ __forceinline__ void g2l16(const u16* g, u16* l) {
  __builtin_amdgcn_global_load_lds(
      (const __attribute__((address_space(1))) unsigned int*)g,
      (__attribute__((address_space(3))) unsigned int*)l, 16, 0, 0);
}

// ---------------- tiled transpose + f32->bf16: dst[c][r] = src[r][c] ----------------
// one 64x64 tile per block; coalesced on both sides.

__global__ __launch_bounds__(256) void tconv(const float* __restrict__ src, int srs,
                                             u16* __restrict__ dst, int drs) {
  __shared__ u16 tile[64][67];
  const int r0 = blockIdx.x * 64, c0 = blockIdx.y * 64;
  const int tlo = threadIdx.x & 63, thi = threadIdx.x >> 6;
#pragma unroll
  for (int i = 0; i < 16; i++) {
    const int r = i * 4 + thi;
    tile[r][tlo] = f2b(src[(size_t)(r0 + r) * srs + c0 + tlo]);
  }
  __syncthreads();
#pragma unroll
  for (int i = 0; i < 16; i++) {
    const int c = i * 4 + thi;
    dst[(size_t)(c0 + c) * drs + r0 + tlo] = tile[tlo][c];
  }
}

// W [H][E][D] -> dst rows n = nbase + h*64 + d, cols e (drs = 512)
__global__ __launch_bounds__(256) void tconv_qkv(const float* __restrict__ W,
                                                 u16* __restrict__ dst0, int nbase) {
  __shared__ u16 tile[64][67];
  const int h = blockIdx.z;
  const float* src = W + (size_t)h * EE * DD;            // [E][D]
  u16* dst = dst0 + (size_t)(nbase + h * 64) * EE;
  const int r0 = blockIdx.x * 64;                        // e-tile
  const int tlo = threadIdx.x & 63, thi = threadIdx.x >> 6;
#pragma unroll
  for (int i = 0; i < 16; i++) {
    const int r = i * 4 + thi;
    tile[r][tlo] = f2b(src[(size_t)(r0 + r) * DD + tlo]);
  }
  __syncthreads();
#pragma unroll
  for (int i = 0; i < 16; i++) {
    const int d = i * 4 + thi;
    dst[(size_t)d * EE + r0 + tlo] = tile[tlo][d];
  }
}

// ---------------- LayerNorm: fp32 in -> bf16 out, one wave per row (E=512) -------

__global__ __launch_bounds__(256) void ln_fwd(const float* __restrict__ xin,
                                              const float* __restrict__ g,
                                              const float* __restrict__ bb,
                                              u16* __restrict__ out) {
  const int wid = threadIdx.x >> 6, lane = threadIdx.x & 63;
  const size_t row = (size_t)blockIdx.x * 4 + wid;
  const float* xr = xin + row * EE + lane * 8;
  float v[8];
  *(float4*)(v)     = *(const float4*)(xr);
  *(float4*)(v + 4) = *(const float4*)(xr + 4);
  float s = 0.f;
#pragma unroll
  for (int j = 0; j < 8; j++) s += v[j];
#pragma unroll
  for (int d = 1; d < 64; d <<= 1) s += __shfl_xor(s, d);
  const float mu = s * (1.f / 512.f);
  float q = 0.f;
#pragma unroll
  for (int j = 0; j < 8; j++) { float dd = v[j] - mu; q += dd * dd; }
#pragma unroll
  for (int d = 1; d < 64; d <<= 1) q += __shfl_xor(q, d);
  const float rstd = rsqrtf(q * (1.f / 512.f) + 1e-5f);
  float gv[8], bv[8];
  *(float4*)(gv)     = *(const float4*)(g + lane * 8);
  *(float4*)(gv + 4) = *(const float4*)(g + lane * 8 + 4);
  *(float4*)(bv)     = *(const float4*)(bb + lane * 8);
  *(float4*)(bv + 4) = *(const float4*)(bb + lane * 8 + 4);
  short8 o;
#pragma unroll
  for (int j = 0; j < 8; j++) o[j] = (short)f2b((v[j] - mu) * rstd * gv[j] + bv[j]);
  *(short8*)(out + row * EE + lane * 8) = o;
}

// ---------------- GEMM (m97 structure): C[M,N] = A[M,K] @ Bt[N,K]^T, bf16 in ----
// 128x128 tile, BK=32, 256 thr = 4 waves (2x2 of 64x64), global_load_lds w16,
// linear LDS, 2-barrier K-loop, XCD-bijective block swizzle.

template <bool BIAS, bool RELU, bool RES, bool OUTBF>
__global__ __launch_bounds__(256) void gemm_bt(const u16* __restrict__ A,
                                               const u16* __restrict__ Bt,
                                               const float* __restrict__ bias,
                                               const float* __restrict__ res,
                                               void* __restrict__ out,
                                               int M, int N, int K) {
  __shared__ u16 As[128 * 32];
  __shared__ u16 Bs[128 * 32];
  const int tid = threadIdx.x;
  const int wid = tid >> 6, lane = tid & 63;
  const int llo = lane & 15, lhi = lane >> 4;
  const int wr = (wid >> 1) * 64, wc = (wid & 1) * 64;

  // XCD-aware swizzle (all grids here have nwg % 8 == 0)
  const int gx = gridDim.x;
  const int nwg = gx * gridDim.y;
  int id = blockIdx.y * gx + blockIdx.x;
  id = (id & 7) * (nwg >> 3) + (id >> 3);
  const size_t row0 = (size_t)(id / gx) * 128;
  const size_t col0 = (size_t)(id % gx) * 128;

  f32x4 acc[4][4];
#pragma unroll
  for (int m = 0; m < 4; m++)
#pragma unroll
    for (int n = 0; n < 4; n++) acc[m][n] = (f32x4){0.f, 0.f, 0.f, 0.f};

  for (int k0 = 0; k0 < K; k0 += 32) {
    __syncthreads();
#pragma unroll
    for (int i = 0; i < 2; i++) {
      const int cb = i * 256 + wid * 64;     // wave-uniform chunk base
      const int c = cb + lane;               // chunk: row = c>>2, col8 = c&3
      g2l16(A + (row0 + (c >> 2)) * K + k0 + (c & 3) * 8, As + cb * 8);
      g2l16(Bt + (col0 + (c >> 2)) * K + k0 + (c & 3) * 8, Bs + cb * 8);
    }
    __syncthreads();
    short8 af[4], bf[4];
#pragma unroll
    for (int m = 0; m < 4; m++) af[m] = *(const short8*)(As + (wr + m * 16 + llo) * 32 + lhi * 8);
#pragma unroll
    for (int n = 0; n < 4; n++) bf[n] = *(const short8*)(Bs + (wc + n * 16 + llo) * 32 + lhi * 8);
#pragma unroll
    for (int m = 0; m < 4; m++)
#pragma unroll
      for (int n = 0; n < 4; n++) acc[m][n] = mfma16(af[m], bf[n], acc[m][n]);
  }

#pragma unroll
  for (int m = 0; m < 4; m++)
#pragma unroll
    for (int r = 0; r < 4; r++) {
      const size_t row = row0 + wr + m * 16 + lhi * 4 + r;
#pragma unroll
      for (int n = 0; n < 4; n++) {
        const size_t col = col0 + wc + n * 16 + llo;
        float v = acc[m][n][r];
        if (BIAS) v += bias[col];
        if (RELU) v = fmaxf(v, 0.f);
        if (RES) v += res[row * (size_t)N + col];
        if (OUTBF) ((u16*)out)[row * (size_t)N + col] = f2b(v);
        else       ((float*)out)[row * (size_t)N + col] = v;
      }
    }
}

// ---------------- Flash attention: one block per (b,h), wave w = Q rows [64w,64w+64) ----
// qkv [BT][1536] bf16 (q|k|v each 512 cols, head h at h*64). ctx [BT][512] bf16.
// V^T staged once per block in LDS (padded) -> PV B-fragment is one ds_read_b128.

__global__ __launch_bounds__(256) void attn_fwd(const u16* __restrict__ qkv,
                                                u16* __restrict__ ctx) {
  const int bh = blockIdx.x;                 // 0..1023
  const int b = bh >> 3, h = bh & 7;
  const int wid = threadIdx.x >> 6;
  const int lane = threadIdx.x & 63;
  const int llo = lane & 15, lhi = lane >> 4;
  const int t0 = wid * 64;

  __shared__ u16 Vt[64][264];                // V^T [d][s], padded (33.8 KB)
  __shared__ u16 Pl[4][64][32];              // per-wave P staging (16 KB)

  const u16* qp = qkv + (size_t)b * TT * 1536 + h * 64;
  const u16* kp = qp + 512;
  const u16* vp = qp + 1024;

  // stage V^T: wave w covers rows [64w, 64w+64); lane: 8 rows x 8 chunks
  {
    const int j = lane & 7;
#pragma unroll
    for (int g8 = 0; g8 < 8; g8++) {
      const int s = wid * 64 + g8 * 8 + (lane >> 3);
      const short8 v = *(const short8*)(vp + (size_t)s * 1536 + j * 8);
#pragma unroll
      for (int jj = 0; jj < 8; jj++) Vt[j * 8 + jj][s] = (u16)v[jj];
    }
  }

  short8 qf[4][2];
#pragma unroll
  for (int m = 0; m < 4; m++)
#pragma unroll
    for (int k2 = 0; k2 < 2; k2++) {
      const int t = t0 + m * 16 + llo;
      qf[m][k2] = *(const short8*)(qp + (size_t)t * 1536 + k2 * 32 + lhi * 8);
    }

  f32x4 O[4][4];
  float mrow[4][4], lrow[4][4];
#pragma unroll
  for (int m = 0; m < 4; m++) {
#pragma unroll
    for (int n = 0; n < 4; n++) O[m][n] = (f32x4){0.f, 0.f, 0.f, 0.f};
#pragma unroll
    for (int r = 0; r < 4; r++) { mrow[m][r] = -1e30f; lrow[m][r] = 0.f; }
  }

  __syncthreads();                            // Vt ready

  const int nst = (t0 + 64) >> 5;             // causal: s-tiles of 32
  for (int st = 0; st < nst; st++) {
    const int s0 = st * 32;
    f32x4 S[4][2];
#pragma unroll
    for (int m = 0; m < 4; m++) {
      S[m][0] = (f32x4){0.f, 0.f, 0.f, 0.f};
      S[m][1] = (f32x4){0.f, 0.f, 0.f, 0.f};
    }
#pragma unroll
    for (int k2 = 0; k2 < 2; k2++) {
      const short8 b0 = *(const short8*)(kp + (size_t)(s0 + llo) * 1536 + k2 * 32 + lhi * 8);
      const short8 b1 = *(const short8*)(kp + (size_t)(s0 + 16 + llo) * 1536 + k2 * 32 + lhi * 8);
#pragma unroll
      for (int m = 0; m < 4; m++) {
        S[m][0] = mfma16(qf[m][k2], b0, S[m][0]);
        S[m][1] = mfma16(qf[m][k2], b1, S[m][1]);
      }
    }
    // online softmax (rows owned by 16-lane groups; reduce over llo)
#pragma unroll
    for (int m = 0; m < 4; m++) {
      float sf[4];
#pragma unroll
      for (int r = 0; r < 4; r++) {
        const int t = t0 + m * 16 + lhi * 4 + r;
        float v0 = S[m][0][r] * 0.125f;
        float v1 = S[m][1][r] * 0.125f;
        if (s0 + llo > t)      v0 = -1e30f;
        if (s0 + 16 + llo > t) v1 = -1e30f;
        float mx = fmaxf(v0, v1);
#pragma unroll
        for (int d = 1; d < 16; d <<= 1) mx = fmaxf(mx, __shfl_xor(mx, d));
        const float mnew = fmaxf(mrow[m][r], mx);
        const float sc = __expf(mrow[m][r] - mnew);
        mrow[m][r] = mnew;
        const float p0 = __expf(v0 - mnew);
        const float p1 = __expf(v1 - mnew);
        float rs = p0 + p1;
#pragma unroll
        for (int d = 1; d < 16; d <<= 1) rs += __shfl_xor(rs, d);
        lrow[m][r] = lrow[m][r] * sc + rs;
        sf[r] = sc;
        const int pr = m * 16 + lhi * 4 + r;
        Pl[wid][pr][llo]      = f2b(p0);
        Pl[wid][pr][llo + 16] = f2b(p1);
      }
#pragma unroll
      for (int n = 0; n < 4; n++)
#pragma unroll
        for (int r = 0; r < 4; r++) O[m][n][r] *= sf[r];
    }
    // PV: O[64,64] += P[64,32] @ V[32,64]
    short8 pf[4];
#pragma unroll
    for (int m = 0; m < 4; m++)
      pf[m] = *(const short8*)(&Pl[wid][m * 16 + llo][lhi * 8]);
#pragma unroll
    for (int n = 0; n < 4; n++) {
      const short8 vf = *(const short8*)(&Vt[n * 16 + llo][s0 + lhi * 8]);
#pragma unroll
      for (int m = 0; m < 4; m++) O[m][n] = mfma16(pf[m], vf, O[m][n]);
    }
  }

#pragma unroll
  for (int m = 0; m < 4; m++)
#pragma unroll
    for (int r = 0; r < 4; r++) {
      const int t = t0 + m * 16 + lhi * 4 + r;
      const float inv = 1.f / lrow[m][r];
      u16* orow = ctx + ((size_t)b * TT + t) * EE + h * 64;
#pragma unroll
      for (int n = 0; n < 4; n++)
        orow[n * 16 + llo] = f2b(O[m][n][r] * inv);
    }
}

// ---------------- launch ----------------

extern "C" void kernel_launch(void* const* d_in, const int* in_sizes, int n_in,
                              void* d_out, int out_size, void* d_ws, size_t ws_size,
                              hipStream_t stream) {
  const float* x   = (const float*)d_in[0];
  const float* Wq  = (const float*)d_in[1];
  const float* Wk  = (const float*)d_in[2];
  const float* Wv  = (const float*)d_in[3];
  const float* Wo  = (const float*)d_in[4];
  const float* bo  = (const float*)d_in[5];
  const float* g1  = (const float*)d_in[6];
  const float* be1 = (const float*)d_in[7];
  const float* g2  = (const float*)d_in[8];
  const float* be2 = (const float*)d_in[9];
  const float* W1  = (const float*)d_in[10];
  const float* b1  = (const float*)d_in[11];
  const float* W2  = (const float*)d_in[12];
  const float* b2  = (const float*)d_in[13];
  float* out = (float*)d_out;

  // workspace layout (~198 MB total)
  char* w = (char*)d_ws;
  u16* WqkvT = (u16*)w;                 w += (size_t)1536 * 512 * 2;   // 1.5 MB
  u16* WoT   = (u16*)w;                 w += (size_t)512 * 512 * 2;    // 0.5 MB
  u16* W1T   = (u16*)w;                 w += (size_t)2048 * 512 * 2;   // 2 MB
  u16* W2T   = (u16*)w;                 w += (size_t)512 * 2048 * 2;   // 2 MB
  u16* hbuf  = (u16*)w;                 w += (size_t)BT * EE * 2;      // 32 MB (h / h2)
  u16* ctxb  = (u16*)w;                 w += (size_t)BT * EE * 2;      // 32 MB
  u16* big   = (u16*)w;                                               // 128 MB (qkv / ff1)
  u16* qkvb = big;
  u16* ff1  = big;

  // 1. weight prep (bf16 + transpose to [N][K]), tiled/coalesced
  tconv_qkv<<<dim3(8, 1, 8), 256, 0, stream>>>(Wq, WqkvT, 0);
  tconv_qkv<<<dim3(8, 1, 8), 256, 0, stream>>>(Wk, WqkvT, 512);
  tconv_qkv<<<dim3(8, 1, 8), 256, 0, stream>>>(Wv, WqkvT, 1024);
  tconv<<<dim3(8, 8),  256, 0, stream>>>(Wo, 512,  WoT, 512);
  tconv<<<dim3(8, 32), 256, 0, stream>>>(W1, 2048, W1T, 512);
  tconv<<<dim3(32, 8), 256, 0, stream>>>(W2, 512,  W2T, 2048);

  // 2. LN1: h = ln(x)
  ln_fwd<<<BT / 4, 256, 0, stream>>>(x, g1, be1, hbuf);

  // 3. QKV: qkv = h @ WqkvT^T   [BT,1536] bf16
  gemm_bt<false, false, false, true><<<dim3(1536 / 128, BT / 128), 256, 0, stream>>>(
      hbuf, WqkvT, nullptr, nullptr, qkvb, BT, 1536, 512);

  // 4. attention -> ctx [BT,512] bf16
  attn_fwd<<<BB * HH, 256, 0, stream>>>(qkvb, ctxb);

  // 5. proj: out1 = ctx @ Wo + bo + x  (fp32, into d_out)
  gemm_bt<true, false, true, false><<<dim3(512 / 128, BT / 128), 256, 0, stream>>>(
      ctxb, WoT, bo, x, out, BT, 512, 512);

  // 6. LN2: h2 = ln(out1)  (reuse hbuf)
  ln_fwd<<<BT / 4, 256, 0, stream>>>(out, g2, be2, hbuf);

  // 7. FFN1: ff1 = relu(h2 @ W1 + b1)  [BT,2048] bf16 (reuses qkv region)
  gemm_bt<true, true, false, true><<<dim3(2048 / 128, BT / 128), 256, 0, stream>>>(
      hbuf, W1T, b1, nullptr, ff1, BT, 2048, 512);

  // 8. FFN2: out = out1 + ff1 @ W2 + b2  (in-place residual on d_out)
  gemm_bt<true, false, true, false><<<dim3(512 / 128, BT / 128), 256, 0, stream>>>(
      ff1, W2T, b2, out, out, BT, 512, 2048);
}